// Round 1
// baseline (11064.140 us; speedup 1.0000x reference)
//
#include <hip/hip_runtime.h>
#include <hip/hip_bf16.h>

#define NWG   64
#define NTHR  512
#define HQ    512
#define ROWB  2048
#define W1OFF 65536

typedef __attribute__((ext_vector_type(8))) short bf16x8;
typedef __attribute__((ext_vector_type(4))) float f32x4;
typedef unsigned short u16;

__device__ __forceinline__ float sigm(float x){ return 1.f/(1.f+__expf(-x)); }
__device__ __forceinline__ float tanhf_(float x){ return 1.f - 2.f/(1.f+__expf(2.f*x)); }
__device__ __forceinline__ u16 f2bf(float x){
  union { float f; unsigned u; } v; v.f = x;
  return (u16)((v.u + 0x7fffu + ((v.u >> 16) & 1u)) >> 16);
}

__device__ __forceinline__ void gridbar(unsigned* cnt, unsigned target){
  __syncthreads();
  if (threadIdx.x == 0){
    __threadfence();
    __hip_atomic_fetch_add(cnt, 1u, __ATOMIC_RELEASE, __HIP_MEMORY_SCOPE_AGENT);
    while (__hip_atomic_load(cnt, __ATOMIC_ACQUIRE, __HIP_MEMORY_SCOPE_AGENT) < target)
      __builtin_amdgcn_s_sleep(1);
  }
  __syncthreads();
}

// One LSTM layer phase: gates = [lo|hi] @ Wcat^T + bias -> h_new (bf16), c in regs.
__device__ __forceinline__ void lstm_phase(
    const char* __restrict__ smemb, int wbase,
    const u16* __restrict__ lo, const u16* __restrict__ hi,
    const float* __restrict__ sbias, u16* __restrict__ dst,
    float* creg, int wg, int w, int lane)
{
  const int col = lane & 15, kg = lane >> 4;
  const int mg = w >> 1, nt = w & 1;
  const int mrow = mg * 32;
  f32x4 acc0 = {0.f,0.f,0.f,0.f}, acc1 = {0.f,0.f,0.f,0.f};
  const int a0o = (mrow + col) * HQ;
  const int a1o = (mrow + 16 + col) * HQ;
  const int brr = nt*16 + col;
  const char* wrow = smemb + wbase + brr*ROWB;
  const int xorm = (brr & 7) << 4;
  #pragma unroll
  for (int k0 = 0; k0 < 512; k0 += 32){
    const int ke = k0 + kg*8;
    bf16x8 b  = *(const bf16x8*)(wrow + ((2*ke) ^ xorm));
    bf16x8 a0 = *(const bf16x8*)(lo + a0o + ke);
    bf16x8 a1 = *(const bf16x8*)(lo + a1o + ke);
    acc0 = __builtin_amdgcn_mfma_f32_16x16x32_bf16(a0, b, acc0, 0, 0, 0);
    acc1 = __builtin_amdgcn_mfma_f32_16x16x32_bf16(a1, b, acc1, 0, 0, 0);
  }
  #pragma unroll
  for (int k0 = 0; k0 < 512; k0 += 32){
    const int ke = k0 + kg*8;
    bf16x8 b  = *(const bf16x8*)(wrow + ((1024 + 2*ke) ^ xorm));
    bf16x8 a0 = *(const bf16x8*)(hi + a0o + ke);
    bf16x8 a1 = *(const bf16x8*)(hi + a1o + ke);
    acc0 = __builtin_amdgcn_mfma_f32_16x16x32_bf16(a0, b, acc0, 0, 0, 0);
    acc1 = __builtin_amdgcn_mfma_f32_16x16x32_bf16(a1, b, acc1, 0, 0, 0);
  }
  const int hc = wg*8 + nt*4 + col;   // valid when col < 4
  #pragma unroll
  for (int mm = 0; mm < 2; ++mm){
    #pragma unroll
    for (int r = 0; r < 4; ++r){
      f32x4 accm = mm ? acc1 : acc0;
      float v = accm[r];
      float vf = __shfl(v, (lane + 4) & 63);
      float vg = __shfl(v, (lane + 8) & 63);
      float vo = __shfl(v, (lane + 12) & 63);
      if (col < 4){
        float vi = v + sbias[nt*16 + col];
        vf += sbias[nt*16 + 4 + col];
        vg += sbias[nt*16 + 8 + col];
        vo += sbias[nt*16 + 12 + col];
        float co = creg[mm*4 + r];
        float cn = sigm(vf)*co + sigm(vi)*tanhf_(vg);
        creg[mm*4 + r] = cn;
        float hv = sigm(vo)*tanhf_(cn);
        const int row = mrow + mm*16 + kg*4 + r;
        dst[row*HQ + hc] = f2bf(hv);
      }
    }
  }
}

__device__ __forceinline__ void out_tile(
    const u16* __restrict__ h1p, const u16* __restrict__ wlinb,
    const float* __restrict__ blin, float* __restrict__ dout,
    int slot, int wg, int w, int lane)
{
  const int col = lane & 15, kg = lane >> 4;
  const int cb = (wg & 15) * 16;
  const int orow = (wg >> 4) * 32 + w * 16;
  f32x4 acc = {0.f,0.f,0.f,0.f};
  const int ao = (orow + col) * HQ;
  const int bo = (cb + col) * HQ;
  #pragma unroll
  for (int k0 = 0; k0 < 512; k0 += 32){
    const int ke = k0 + kg*8;
    bf16x8 a = *(const bf16x8*)(h1p + ao + ke);
    bf16x8 b = *(const bf16x8*)(wlinb + bo + ke);
    acc = __builtin_amdgcn_mfma_f32_16x16x32_bf16(a, b, acc, 0, 0, 0);
  }
  const float bl = blin[cb + col];
  #pragma unroll
  for (int r = 0; r < 4; ++r){
    const int row = orow + kg*4 + r;
    dout[(size_t)slot*32768 + row*256 + cb + col] = acc[r] + bl;
  }
}

__global__ __launch_bounds__(NTHR, 2) void lstm_ae_kernel(
  const float* __restrict__ initial_hidden,
  const float* __restrict__ Wih0, const float* __restrict__ Whh0,
  const float* __restrict__ bih0, const float* __restrict__ bhh0,
  const float* __restrict__ Wih1, const float* __restrict__ Whh1,
  const float* __restrict__ bih1, const float* __restrict__ bhh1,
  const float* __restrict__ Wlin, const float* __restrict__ blin,
  const int* __restrict__ seqp,
  float* __restrict__ dout, char* __restrict__ ws)
{
  __shared__ __align__(128) char wsmem[131072];
  __shared__ float s_b0[32], s_b1[32];
  const int tid = threadIdx.x, wg = blockIdx.x;
  const int w = tid >> 6, lane = tid & 63;
  const int T = seqp[0];

  unsigned* cnt = (unsigned*)ws;
  u16* h0b[2]; u16* h1b[2];
  h0b[0] = (u16*)(ws + 1024);
  h0b[1] = h0b[0] + 65536;
  h1b[0] = h0b[1] + 65536;
  h1b[1] = h1b[0] + 65536;
  u16* wlinb = h1b[1] + 65536;

  // ---------------- prologue ----------------
  // stage this WG's 32 Wih0 rows (f32) into the W1 LDS area temporarily
  float* sw = (float*)(wsmem + W1OFF);
  for (int it = tid; it < 32*256; it += NTHR){
    const int rr = it >> 8, d = it & 255;
    const int j = ((rr >> 2) & 3)*512 + wg*8 + (rr >> 4)*4 + (rr & 3);
    sw[it] = Wih0[j*256 + d];
  }
  __syncthreads();
  // Weff = Wih0 @ Wlin  -> W0 low half (k<512), bf16, swizzled
  {
    float acc[32];
    #pragma unroll
    for (int rr = 0; rr < 32; ++rr) acc[rr] = 0.f;
    for (int d = 0; d < 256; d += 4){
      const float wl0 = Wlin[(d+0)*512 + tid];
      const float wl1 = Wlin[(d+1)*512 + tid];
      const float wl2 = Wlin[(d+2)*512 + tid];
      const float wl3 = Wlin[(d+3)*512 + tid];
      #pragma unroll
      for (int rr = 0; rr < 32; ++rr){
        const f32x4 s4 = *(const f32x4*)(sw + rr*256 + d);
        acc[rr] += s4[0]*wl0 + s4[1]*wl1 + s4[2]*wl2 + s4[3]*wl3;
      }
    }
    #pragma unroll
    for (int rr = 0; rr < 32; ++rr){
      *(u16*)(wsmem + rr*ROWB + ((2*tid) ^ ((rr & 7) << 4))) = f2bf(acc[rr]);
    }
  }
  // biases: b0eff = bih0+bhh0+Wih0@blin ; b1 = bih1+bhh1
  if (tid < 32){
    const int rr = tid;
    const int j = ((rr >> 2) & 3)*512 + wg*8 + (rr >> 4)*4 + (rr & 3);
    float s = bih0[j] + bhh0[j];
    for (int d = 0; d < 256; ++d) s += sw[rr*256 + d] * blin[d];
    s_b0[rr] = s;
  } else if (tid < 64){
    const int rr = tid - 32;
    const int j = ((rr >> 2) & 3)*512 + wg*8 + (rr >> 4)*4 + (rr & 3);
    s_b1[rr] = bih1[j] + bhh1[j];
  }
  __syncthreads();
  // W0 high half: Whh0 (k>=512)
  for (int it = tid; it < 32*512; it += NTHR){
    const int rr = it >> 9, kk = it & 511;
    const int j = ((rr >> 2) & 3)*512 + wg*8 + (rr >> 4)*4 + (rr & 3);
    *(u16*)(wsmem + rr*ROWB + ((1024 + 2*kk) ^ ((rr & 7) << 4))) = f2bf(Whh0[j*512 + kk]);
  }
  // W1 = [Wih1 | Whh1]
  for (int it = tid; it < 32*1024; it += NTHR){
    const int rr = it >> 10, e = it & 1023;
    const int j = ((rr >> 2) & 3)*512 + wg*8 + (rr >> 4)*4 + (rr & 3);
    const float v = (e < 512) ? Wih1[j*512 + e] : Whh1[j*512 + (e - 512)];
    *(u16*)(wsmem + W1OFF + rr*ROWB + ((2*e) ^ ((rr & 7) << 4))) = f2bf(v);
  }
  // global inits: h0 = initial_hidden[1], h1 = initial_hidden[0] (reference reverses)
  for (int i = wg*1024 + tid; i < (wg + 1)*1024; i += NTHR){
    h0b[0][i] = f2bf(initial_hidden[65536 + i]);
    h1b[0][i] = f2bf(initial_hidden[i]);
  }
  for (int i = wg*2048 + tid; i < (wg + 1)*2048; i += NTHR){
    wlinb[i] = f2bf(Wlin[i]);
  }

  unsigned barno = 0;
  gridbar(cnt, ++barno * NWG);

  float c0r[8], c1r[8];
  #pragma unroll
  for (int q = 0; q < 8; ++q){ c0r[q] = 0.f; c1r[q] = 0.f; }

  int p = 0;
  for (int s = 1; s < T; ++s){
    const u16* h0p = h0b[p]; u16* h0n = h0b[p ^ 1];
    const u16* h1p = h1b[p]; u16* h1n = h1b[p ^ 1];
    // phase 1: gates0 = h1_prev@Weff^T + h0_prev@Whh0^T  (+ out(s-1) on waves 0,1)
    lstm_phase(wsmem, 0, h1p, h0p, s_b0, h0n, c0r, wg, w, lane);
    if (w < 2) out_tile(h1p, wlinb, blin, dout, T - s, wg, w, lane);
    gridbar(cnt, ++barno * NWG);
    // phase 2: gates1 = h0_new@Wih1^T + h1_prev@Whh1^T
    lstm_phase(wsmem, W1OFF, h0n, h1p, s_b1, h1n, c1r, wg, w, lane);
    gridbar(cnt, ++barno * NWG);
    p ^= 1;
  }
  if (w < 2) out_tile(h1b[p], wlinb, blin, dout, 0, wg, w, lane);
}

extern "C" void kernel_launch(void* const* d_in, const int* in_sizes, int n_in,
                              void* d_out, int out_size, void* d_ws, size_t ws_size,
                              hipStream_t stream) {
  const float* initial_hidden = (const float*)d_in[0];
  const float* Wih0 = (const float*)d_in[1];
  const float* Whh0 = (const float*)d_in[2];
  const float* bih0 = (const float*)d_in[3];
  const float* bhh0 = (const float*)d_in[4];
  const float* Wih1 = (const float*)d_in[5];
  const float* Whh1 = (const float*)d_in[6];
  const float* bih1 = (const float*)d_in[7];
  const float* bhh1 = (const float*)d_in[8];
  const float* Wlin = (const float*)d_in[9];
  const float* blin = (const float*)d_in[10];
  const int*   seqp = (const int*)d_in[11];

  hipMemsetAsync(d_ws, 0, 1024, stream);
  lstm_ae_kernel<<<dim3(NWG), dim3(NTHR), 0, stream>>>(
      initial_hidden, Wih0, Whh0, bih0, bhh0, Wih1, Whh1, bih1, bhh1,
      Wlin, blin, seqp, (float*)d_out, (char*)d_ws);
}

// Round 2
// 7427.600 us; speedup vs baseline: 1.4896x; 1.4896x over previous
//
#include <hip/hip_runtime.h>
#include <hip/hip_bf16.h>

#define NWG   64
#define NTHR  512
#define HQ    512
#define ROWB  2048
#define W1OFF 65536

typedef __attribute__((ext_vector_type(8))) short bf16x8;
typedef __attribute__((ext_vector_type(4))) float f32x4;
typedef unsigned short u16;

__device__ __forceinline__ float sigm(float x){ return 1.f/(1.f+__expf(-x)); }
__device__ __forceinline__ float tanhf_(float x){ return 1.f - 2.f/(1.f+__expf(2.f*x)); }
__device__ __forceinline__ u16 f2bf(float x){
  union { float f; unsigned u; } v; v.f = x;
  return (u16)((v.u + 0x7fffu + ((v.u >> 16) & 1u)) >> 16);
}

// Grid barrier: release only on the add (one buffer_wbl2), RELAXED spin loads
// (no per-poll L2 invalidate), one acquire fence at exit (one buffer_inv).
__device__ __forceinline__ void gridbar(unsigned* cnt, unsigned target){
  __syncthreads();   // drains each wave's vmcnt (stores are in L2 before wbl2)
  if (threadIdx.x == 0){
    __hip_atomic_fetch_add(cnt, 1u, __ATOMIC_RELEASE, __HIP_MEMORY_SCOPE_AGENT);
    while (__hip_atomic_load(cnt, __ATOMIC_RELAXED, __HIP_MEMORY_SCOPE_AGENT) < target)
      __builtin_amdgcn_s_sleep(1);
    __builtin_amdgcn_fence(__ATOMIC_ACQUIRE, "agent");
  }
  __syncthreads();
}

// One LSTM layer phase: gates = [lo|hi] @ Wcat^T + bias -> h_new (bf16), c in regs.
// Per-wave tile: M=16 (rows w*16..+16), N=32 (both n-tiles) -> A loaded once per WG.
__device__ __forceinline__ void lstm_phase(
    const char* __restrict__ smemb, int wbase,
    const u16* __restrict__ lo, const u16* __restrict__ hi,
    const float* __restrict__ sbias, u16* __restrict__ dst,
    float* creg, int wg, int w, int lane)
{
  const int col = lane & 15, kg = lane >> 4;
  const int mrow = w * 16;
  f32x4 acc0 = {0.f,0.f,0.f,0.f}, acc1 = {0.f,0.f,0.f,0.f};
  const int ao = (mrow + col) * HQ;
  const char* w0 = smemb + wbase + col * ROWB;          // n-tile 0, B-row = col
  const char* w1 = smemb + wbase + (16 + col) * ROWB;   // n-tile 1, B-row = 16+col
  const int x0 = (col & 7) << 4;                        // (16+col)&7 == col&7
  #pragma unroll
  for (int k0 = 0; k0 < 512; k0 += 32){
    const int ke = k0 + kg*8;
    bf16x8 a  = *(const bf16x8*)(lo + ao + ke);
    bf16x8 b0 = *(const bf16x8*)(w0 + ((2*ke) ^ x0));
    bf16x8 b1 = *(const bf16x8*)(w1 + ((2*ke) ^ x0));
    acc0 = __builtin_amdgcn_mfma_f32_16x16x32_bf16(a, b0, acc0, 0, 0, 0);
    acc1 = __builtin_amdgcn_mfma_f32_16x16x32_bf16(a, b1, acc1, 0, 0, 0);
  }
  #pragma unroll
  for (int k0 = 0; k0 < 512; k0 += 32){
    const int ke = k0 + kg*8;
    bf16x8 a  = *(const bf16x8*)(hi + ao + ke);
    bf16x8 b0 = *(const bf16x8*)(w0 + ((1024 + 2*ke) ^ x0));
    bf16x8 b1 = *(const bf16x8*)(w1 + ((1024 + 2*ke) ^ x0));
    acc0 = __builtin_amdgcn_mfma_f32_16x16x32_bf16(a, b0, acc0, 0, 0, 0);
    acc1 = __builtin_amdgcn_mfma_f32_16x16x32_bf16(a, b1, acc1, 0, 0, 0);
  }
  const int hcb = wg * 8;
  #pragma unroll
  for (int nt = 0; nt < 2; ++nt){
    f32x4 accm = nt ? acc1 : acc0;
    #pragma unroll
    for (int r = 0; r < 4; ++r){
      float v = accm[r];
      float vf = __shfl(v, (lane + 4) & 63);
      float vg = __shfl(v, (lane + 8) & 63);
      float vo = __shfl(v, (lane + 12) & 63);
      if (col < 4){
        float vi = v + sbias[nt*16 + col];
        vf += sbias[nt*16 + 4 + col];
        vg += sbias[nt*16 + 8 + col];
        vo += sbias[nt*16 + 12 + col];
        float co = creg[nt*4 + r];
        float cn = sigm(vf)*co + sigm(vi)*tanhf_(vg);
        creg[nt*4 + r] = cn;
        float hv = sigm(vo)*tanhf_(cn);
        const int row = mrow + kg*4 + r;
        dst[row*HQ + hcb + nt*4 + col] = f2bf(hv);
      }
    }
  }
}

__device__ __forceinline__ void out_tile(
    const u16* __restrict__ h1p, const u16* __restrict__ wlinb,
    const float* __restrict__ blin, float* __restrict__ dout,
    int slot, int wg, int w, int lane)
{
  const int col = lane & 15, kg = lane >> 4;
  const int cb = (wg & 15) * 16;
  const int orow = (wg >> 4) * 32 + w * 16;
  f32x4 acc = {0.f,0.f,0.f,0.f};
  const int ao = (orow + col) * HQ;
  const int bo = (cb + col) * HQ;
  #pragma unroll
  for (int k0 = 0; k0 < 512; k0 += 32){
    const int ke = k0 + kg*8;
    bf16x8 a = *(const bf16x8*)(h1p + ao + ke);
    bf16x8 b = *(const bf16x8*)(wlinb + bo + ke);
    acc = __builtin_amdgcn_mfma_f32_16x16x32_bf16(a, b, acc, 0, 0, 0);
  }
  const float bl = blin[cb + col];
  #pragma unroll
  for (int r = 0; r < 4; ++r){
    const int row = orow + kg*4 + r;
    dout[(size_t)slot*32768 + row*256 + cb + col] = acc[r] + bl;
  }
}

__global__ __launch_bounds__(NTHR, 2) void lstm_ae_kernel(
  const float* __restrict__ initial_hidden,
  const float* __restrict__ Wih0, const float* __restrict__ Whh0,
  const float* __restrict__ bih0, const float* __restrict__ bhh0,
  const float* __restrict__ Wih1, const float* __restrict__ Whh1,
  const float* __restrict__ bih1, const float* __restrict__ bhh1,
  const float* __restrict__ Wlin, const float* __restrict__ blin,
  const int* __restrict__ seqp,
  float* __restrict__ dout, char* __restrict__ ws)
{
  __shared__ __align__(128) char wsmem[131072];
  __shared__ float s_b0[32], s_b1[32];
  const int tid = threadIdx.x, wg = blockIdx.x;
  const int w = tid >> 6, lane = tid & 63;
  const int T = seqp[0];

  unsigned* cnt = (unsigned*)ws;
  u16* h0b[2]; u16* h1b[2];
  h0b[0] = (u16*)(ws + 1024);
  h0b[1] = h0b[0] + 65536;
  h1b[0] = h0b[1] + 65536;
  h1b[1] = h1b[0] + 65536;
  u16* wlinb = h1b[1] + 65536;

  // ---------------- prologue (identical to validated round 1) ----------------
  float* sw = (float*)(wsmem + W1OFF);
  for (int it = tid; it < 32*256; it += NTHR){
    const int rr = it >> 8, d = it & 255;
    const int j = ((rr >> 2) & 3)*512 + wg*8 + (rr >> 4)*4 + (rr & 3);
    sw[it] = Wih0[j*256 + d];
  }
  __syncthreads();
  {
    float acc[32];
    #pragma unroll
    for (int rr = 0; rr < 32; ++rr) acc[rr] = 0.f;
    for (int d = 0; d < 256; d += 4){
      const float wl0 = Wlin[(d+0)*512 + tid];
      const float wl1 = Wlin[(d+1)*512 + tid];
      const float wl2 = Wlin[(d+2)*512 + tid];
      const float wl3 = Wlin[(d+3)*512 + tid];
      #pragma unroll
      for (int rr = 0; rr < 32; ++rr){
        const f32x4 s4 = *(const f32x4*)(sw + rr*256 + d);
        acc[rr] += s4[0]*wl0 + s4[1]*wl1 + s4[2]*wl2 + s4[3]*wl3;
      }
    }
    #pragma unroll
    for (int rr = 0; rr < 32; ++rr){
      *(u16*)(wsmem + rr*ROWB + ((2*tid) ^ ((rr & 7) << 4))) = f2bf(acc[rr]);
    }
  }
  if (tid < 32){
    const int rr = tid;
    const int j = ((rr >> 2) & 3)*512 + wg*8 + (rr >> 4)*4 + (rr & 3);
    float s = bih0[j] + bhh0[j];
    for (int d = 0; d < 256; ++d) s += sw[rr*256 + d] * blin[d];
    s_b0[rr] = s;
  } else if (tid < 64){
    const int rr = tid - 32;
    const int j = ((rr >> 2) & 3)*512 + wg*8 + (rr >> 4)*4 + (rr & 3);
    s_b1[rr] = bih1[j] + bhh1[j];
  }
  __syncthreads();
  for (int it = tid; it < 32*512; it += NTHR){
    const int rr = it >> 9, kk = it & 511;
    const int j = ((rr >> 2) & 3)*512 + wg*8 + (rr >> 4)*4 + (rr & 3);
    *(u16*)(wsmem + rr*ROWB + ((1024 + 2*kk) ^ ((rr & 7) << 4))) = f2bf(Whh0[j*512 + kk]);
  }
  for (int it = tid; it < 32*1024; it += NTHR){
    const int rr = it >> 10, e = it & 1023;
    const int j = ((rr >> 2) & 3)*512 + wg*8 + (rr >> 4)*4 + (rr & 3);
    const float v = (e < 512) ? Wih1[j*512 + e] : Whh1[j*512 + (e - 512)];
    *(u16*)(wsmem + W1OFF + rr*ROWB + ((2*e) ^ ((rr & 7) << 4))) = f2bf(v);
  }
  for (int i = wg*1024 + tid; i < (wg + 1)*1024; i += NTHR){
    h0b[0][i] = f2bf(initial_hidden[65536 + i]);
    h1b[0][i] = f2bf(initial_hidden[i]);
  }
  for (int i = wg*2048 + tid; i < (wg + 1)*2048; i += NTHR){
    wlinb[i] = f2bf(Wlin[i]);
  }

  unsigned barno = 0;
  gridbar(cnt, ++barno * NWG);

  float c0r[8], c1r[8];
  #pragma unroll
  for (int q = 0; q < 8; ++q){ c0r[q] = 0.f; c1r[q] = 0.f; }

  int p = 0;
  for (int s = 1; s < T; ++s){
    const u16* h0p = h0b[p]; u16* h0n = h0b[p ^ 1];
    const u16* h1p = h1b[p]; u16* h1n = h1b[p ^ 1];
    // phase 1: gates0 = h1_prev@Weff^T + h0_prev@Whh0^T  (+ out(s-1) on waves 0,1)
    lstm_phase(wsmem, 0, h1p, h0p, s_b0, h0n, c0r, wg, w, lane);
    if (w < 2) out_tile(h1p, wlinb, blin, dout, T - s, wg, w, lane);
    gridbar(cnt, ++barno * NWG);
    // phase 2: gates1 = h0_new@Wih1^T + h1_prev@Whh1^T
    lstm_phase(wsmem, W1OFF, h0n, h1p, s_b1, h1n, c1r, wg, w, lane);
    gridbar(cnt, ++barno * NWG);
    p ^= 1;
  }
  if (w < 2) out_tile(h1b[p], wlinb, blin, dout, 0, wg, w, lane);
}

extern "C" void kernel_launch(void* const* d_in, const int* in_sizes, int n_in,
                              void* d_out, int out_size, void* d_ws, size_t ws_size,
                              hipStream_t stream) {
  const float* initial_hidden = (const float*)d_in[0];
  const float* Wih0 = (const float*)d_in[1];
  const float* Whh0 = (const float*)d_in[2];
  const float* bih0 = (const float*)d_in[3];
  const float* bhh0 = (const float*)d_in[4];
  const float* Wih1 = (const float*)d_in[5];
  const float* Whh1 = (const float*)d_in[6];
  const float* bih1 = (const float*)d_in[7];
  const float* bhh1 = (const float*)d_in[8];
  const float* Wlin = (const float*)d_in[9];
  const float* blin = (const float*)d_in[10];
  const int*   seqp = (const int*)d_in[11];

  hipMemsetAsync(d_ws, 0, 1024, stream);
  lstm_ae_kernel<<<dim3(NWG), dim3(NTHR), 0, stream>>>(
      initial_hidden, Wih0, Whh0, bih0, bhh0, Wih1, Whh1, bih1, bhh1,
      Wlin, blin, seqp, (float*)d_out, (char*)d_ws);
}

// Round 3
// 6895.831 us; speedup vs baseline: 1.6045x; 1.0771x over previous
//
#include <hip/hip_runtime.h>
#include <hip/hip_bf16.h>

#define NWG   64
#define NTHR  512
#define HQ    512
#define ROWB  2048
#define W1OFF 65536

typedef __attribute__((ext_vector_type(8))) short bf16x8;
typedef __attribute__((ext_vector_type(4))) float f32x4;
typedef unsigned short u16;

__device__ __forceinline__ float sigm(float x){ return 1.f/(1.f+__expf(-x)); }
__device__ __forceinline__ float tanhf_(float x){ return 1.f - 2.f/(1.f+__expf(2.f*x)); }
__device__ __forceinline__ u16 f2bf(float x){
  union { float f; unsigned u; } v; v.f = x;
  return (u16)((v.u + 0x7fffu + ((v.u >> 16) & 1u)) >> 16);
}

// Fan-out/fan-in grid barrier: no atomic RMW.
// bar[wg*16]   : per-WG arrival epoch (one 64B line per WG)
// bar[64*16]   : go epoch (published by WG0)
__device__ __forceinline__ void gridbar(unsigned* bar, unsigned barno, int wg){
  __syncthreads();
  if (threadIdx.x < 64){
    if (threadIdx.x == 0){
      __builtin_amdgcn_fence(__ATOMIC_RELEASE, "agent");   // one wbl2: h-data -> LLC
      __hip_atomic_store(&bar[wg*16], barno, __ATOMIC_RELAXED, __HIP_MEMORY_SCOPE_AGENT);
    }
    if (wg == 0){
      // wave 0 of WG0: lane i watches WG i's flag; wave reconverges when all set
      unsigned* f = &bar[threadIdx.x*16];
      while (__hip_atomic_load(f, __ATOMIC_RELAXED, __HIP_MEMORY_SCOPE_AGENT) < barno)
        __builtin_amdgcn_s_sleep(1);
      if (threadIdx.x == 0)
        __hip_atomic_store(&bar[64*16], barno, __ATOMIC_RELAXED, __HIP_MEMORY_SCOPE_AGENT);
    } else if (threadIdx.x == 0){
      while (__hip_atomic_load(&bar[64*16], __ATOMIC_RELAXED, __HIP_MEMORY_SCOPE_AGENT) < barno)
        __builtin_amdgcn_s_sleep(1);
    }
    __builtin_amdgcn_fence(__ATOMIC_ACQUIRE, "agent");     // one buffer_inv
  }
  __syncthreads();
}

// One LSTM layer phase: gates = [lo|hi] @ Wcat^T + bias -> h_new (bf16), c in regs.
// Per-wave tile: M=16 (rows w*16..+16), N=32 (both n-tiles) -> A loaded once per WG.
__device__ __forceinline__ void lstm_phase(
    const char* __restrict__ smemb, int wbase,
    const u16* __restrict__ lo, const u16* __restrict__ hi,
    const float* __restrict__ sbias, u16* __restrict__ dst,
    float* creg, int wg, int w, int lane)
{
  const int col = lane & 15, kg = lane >> 4;
  const int mrow = w * 16;
  f32x4 acc0 = {0.f,0.f,0.f,0.f}, acc1 = {0.f,0.f,0.f,0.f};
  const int ao = (mrow + col) * HQ;
  const char* w0 = smemb + wbase + col * ROWB;          // n-tile 0, B-row = col
  const char* w1 = smemb + wbase + (16 + col) * ROWB;   // n-tile 1, B-row = 16+col
  const int x0 = (col & 7) << 4;                        // (16+col)&7 == col&7
  #pragma unroll
  for (int k0 = 0; k0 < 512; k0 += 32){
    const int ke = k0 + kg*8;
    bf16x8 a  = *(const bf16x8*)(lo + ao + ke);
    bf16x8 b0 = *(const bf16x8*)(w0 + ((2*ke) ^ x0));
    bf16x8 b1 = *(const bf16x8*)(w1 + ((2*ke) ^ x0));
    acc0 = __builtin_amdgcn_mfma_f32_16x16x32_bf16(a, b0, acc0, 0, 0, 0);
    acc1 = __builtin_amdgcn_mfma_f32_16x16x32_bf16(a, b1, acc1, 0, 0, 0);
  }
  #pragma unroll
  for (int k0 = 0; k0 < 512; k0 += 32){
    const int ke = k0 + kg*8;
    bf16x8 a  = *(const bf16x8*)(hi + ao + ke);
    bf16x8 b0 = *(const bf16x8*)(w0 + ((1024 + 2*ke) ^ x0));
    bf16x8 b1 = *(const bf16x8*)(w1 + ((1024 + 2*ke) ^ x0));
    acc0 = __builtin_amdgcn_mfma_f32_16x16x32_bf16(a, b0, acc0, 0, 0, 0);
    acc1 = __builtin_amdgcn_mfma_f32_16x16x32_bf16(a, b1, acc1, 0, 0, 0);
  }
  const int hcb = wg * 8;
  #pragma unroll
  for (int nt = 0; nt < 2; ++nt){
    f32x4 accm = nt ? acc1 : acc0;
    #pragma unroll
    for (int r = 0; r < 4; ++r){
      float v = accm[r];
      float vf = __shfl(v, (lane + 4) & 63);
      float vg = __shfl(v, (lane + 8) & 63);
      float vo = __shfl(v, (lane + 12) & 63);
      if (col < 4){
        float vi = v + sbias[nt*16 + col];
        vf += sbias[nt*16 + 4 + col];
        vg += sbias[nt*16 + 8 + col];
        vo += sbias[nt*16 + 12 + col];
        float co = creg[nt*4 + r];
        float cn = sigm(vf)*co + sigm(vi)*tanhf_(vg);
        creg[nt*4 + r] = cn;
        float hv = sigm(vo)*tanhf_(cn);
        const int row = mrow + kg*4 + r;
        dst[row*HQ + hcb + nt*4 + col] = f2bf(hv);
      }
    }
  }
}

__device__ __forceinline__ void out_tile(
    const u16* __restrict__ h1p, const u16* __restrict__ wlinb,
    const float* __restrict__ blin, float* __restrict__ dout,
    int slot, int wg, int w, int lane)
{
  const int col = lane & 15, kg = lane >> 4;
  const int cb = (wg & 15) * 16;
  const int orow = (wg >> 4) * 32 + w * 16;
  f32x4 acc = {0.f,0.f,0.f,0.f};
  const int ao = (orow + col) * HQ;
  const int bo = (cb + col) * HQ;
  #pragma unroll
  for (int k0 = 0; k0 < 512; k0 += 32){
    const int ke = k0 + kg*8;
    bf16x8 a = *(const bf16x8*)(h1p + ao + ke);
    bf16x8 b = *(const bf16x8*)(wlinb + bo + ke);
    acc = __builtin_amdgcn_mfma_f32_16x16x32_bf16(a, b, acc, 0, 0, 0);
  }
  const float bl = blin[cb + col];
  #pragma unroll
  for (int r = 0; r < 4; ++r){
    const int row = orow + kg*4 + r;
    dout[(size_t)slot*32768 + row*256 + cb + col] = acc[r] + bl;
  }
}

__global__ __launch_bounds__(NTHR, 2) void lstm_ae_kernel(
  const float* __restrict__ initial_hidden,
  const float* __restrict__ Wih0, const float* __restrict__ Whh0,
  const float* __restrict__ bih0, const float* __restrict__ bhh0,
  const float* __restrict__ Wih1, const float* __restrict__ Whh1,
  const float* __restrict__ bih1, const float* __restrict__ bhh1,
  const float* __restrict__ Wlin, const float* __restrict__ blin,
  const int* __restrict__ seqp,
  float* __restrict__ dout, char* __restrict__ ws)
{
  __shared__ __align__(128) char wsmem[131072];
  __shared__ float s_b0[32], s_b1[32];
  const int tid = threadIdx.x, wg = blockIdx.x;
  const int w = tid >> 6, lane = tid & 63;
  const int T = seqp[0];

  unsigned* bar = (unsigned*)ws;            // 8 KB: 64 arrival lines + go word
  u16* h0b[2]; u16* h1b[2];
  h0b[0] = (u16*)(ws + 8192);
  h0b[1] = h0b[0] + 65536;
  h1b[0] = h0b[1] + 65536;
  h1b[1] = h1b[0] + 65536;
  u16* wlinb = h1b[1] + 65536;

  // ---------------- prologue (identical to validated round 1/2) ----------------
  float* sw = (float*)(wsmem + W1OFF);
  for (int it = tid; it < 32*256; it += NTHR){
    const int rr = it >> 8, d = it & 255;
    const int j = ((rr >> 2) & 3)*512 + wg*8 + (rr >> 4)*4 + (rr & 3);
    sw[it] = Wih0[j*256 + d];
  }
  __syncthreads();
  {
    float acc[32];
    #pragma unroll
    for (int rr = 0; rr < 32; ++rr) acc[rr] = 0.f;
    for (int d = 0; d < 256; d += 4){
      const float wl0 = Wlin[(d+0)*512 + tid];
      const float wl1 = Wlin[(d+1)*512 + tid];
      const float wl2 = Wlin[(d+2)*512 + tid];
      const float wl3 = Wlin[(d+3)*512 + tid];
      #pragma unroll
      for (int rr = 0; rr < 32; ++rr){
        const f32x4 s4 = *(const f32x4*)(sw + rr*256 + d);
        acc[rr] += s4[0]*wl0 + s4[1]*wl1 + s4[2]*wl2 + s4[3]*wl3;
      }
    }
    #pragma unroll
    for (int rr = 0; rr < 32; ++rr){
      *(u16*)(wsmem + rr*ROWB + ((2*tid) ^ ((rr & 7) << 4))) = f2bf(acc[rr]);
    }
  }
  if (tid < 32){
    const int rr = tid;
    const int j = ((rr >> 2) & 3)*512 + wg*8 + (rr >> 4)*4 + (rr & 3);
    float s = bih0[j] + bhh0[j];
    for (int d = 0; d < 256; ++d) s += sw[rr*256 + d] * blin[d];
    s_b0[rr] = s;
  } else if (tid < 64){
    const int rr = tid - 32;
    const int j = ((rr >> 2) & 3)*512 + wg*8 + (rr >> 4)*4 + (rr & 3);
    s_b1[rr] = bih1[j] + bhh1[j];
  }
  __syncthreads();
  for (int it = tid; it < 32*512; it += NTHR){
    const int rr = it >> 9, kk = it & 511;
    const int j = ((rr >> 2) & 3)*512 + wg*8 + (rr >> 4)*4 + (rr & 3);
    *(u16*)(wsmem + rr*ROWB + ((1024 + 2*kk) ^ ((rr & 7) << 4))) = f2bf(Whh0[j*512 + kk]);
  }
  for (int it = tid; it < 32*1024; it += NTHR){
    const int rr = it >> 10, e = it & 1023;
    const int j = ((rr >> 2) & 3)*512 + wg*8 + (rr >> 4)*4 + (rr & 3);
    const float v = (e < 512) ? Wih1[j*512 + e] : Whh1[j*512 + (e - 512)];
    *(u16*)(wsmem + W1OFF + rr*ROWB + ((2*e) ^ ((rr & 7) << 4))) = f2bf(v);
  }
  for (int i = wg*1024 + tid; i < (wg + 1)*1024; i += NTHR){
    h0b[0][i] = f2bf(initial_hidden[65536 + i]);
    h1b[0][i] = f2bf(initial_hidden[i]);
  }
  for (int i = wg*2048 + tid; i < (wg + 1)*2048; i += NTHR){
    wlinb[i] = f2bf(Wlin[i]);
  }

  unsigned barno = 0;
  gridbar(bar, ++barno, wg);

  float c0r[8], c1r[8];
  #pragma unroll
  for (int q = 0; q < 8; ++q){ c0r[q] = 0.f; c1r[q] = 0.f; }

  int p = 0;
  for (int s = 1; s < T; ++s){
    const u16* h0p = h0b[p]; u16* h0n = h0b[p ^ 1];
    const u16* h1p = h1b[p]; u16* h1n = h1b[p ^ 1];
    // phase 1: gates0 = h1_prev@Weff^T + h0_prev@Whh0^T  (+ out(s-1) on waves 0,1)
    lstm_phase(wsmem, 0, h1p, h0p, s_b0, h0n, c0r, wg, w, lane);
    if (w < 2) out_tile(h1p, wlinb, blin, dout, T - s, wg, w, lane);
    gridbar(bar, ++barno, wg);
    // phase 2: gates1 = h0_new@Wih1^T + h1_prev@Whh1^T
    lstm_phase(wsmem, W1OFF, h0n, h1p, s_b1, h1n, c1r, wg, w, lane);
    gridbar(bar, ++barno, wg);
    p ^= 1;
  }
  if (w < 2) out_tile(h1b[p], wlinb, blin, dout, 0, wg, w, lane);
}

extern "C" void kernel_launch(void* const* d_in, const int* in_sizes, int n_in,
                              void* d_out, int out_size, void* d_ws, size_t ws_size,
                              hipStream_t stream) {
  const float* initial_hidden = (const float*)d_in[0];
  const float* Wih0 = (const float*)d_in[1];
  const float* Whh0 = (const float*)d_in[2];
  const float* bih0 = (const float*)d_in[3];
  const float* bhh0 = (const float*)d_in[4];
  const float* Wih1 = (const float*)d_in[5];
  const float* Whh1 = (const float*)d_in[6];
  const float* bih1 = (const float*)d_in[7];
  const float* bhh1 = (const float*)d_in[8];
  const float* Wlin = (const float*)d_in[9];
  const float* blin = (const float*)d_in[10];
  const int*   seqp = (const int*)d_in[11];

  hipMemsetAsync(d_ws, 0, 8192, stream);
  lstm_ae_kernel<<<dim3(NWG), dim3(NTHR), 0, stream>>>(
      initial_hidden, Wih0, Whh0, bih0, bhh0, Wih1, Whh1, bih1, bhh1,
      Wlin, blin, seqp, (float*)d_out, (char*)d_ws);
}